// Round 10
// baseline (77.503 us; speedup 1.0000x reference)
//
#include <hip/hip_runtime.h>
#include <math.h>

#define TT 1024
#define DD 128

static constexpr float kNegInf = -1e9f;

typedef __fp16 h2 __attribute__((ext_vector_type(2)));

__device__ __forceinline__ unsigned int pk16(float a, float b) {
  h2 v = __builtin_amdgcn_cvt_pkrtz(a, b);
  return __builtin_bit_cast(unsigned int, v);
}
__device__ __forceinline__ float dot2f(unsigned int a, unsigned int b, float c) {
#if __has_builtin(__builtin_amdgcn_fdot2)
  return __builtin_amdgcn_fdot2(__builtin_bit_cast(h2, a),
                                __builtin_bit_cast(h2, b), c, false);
#else
  h2 av = __builtin_bit_cast(h2, a), bv = __builtin_bit_cast(h2, b);
  return c + (float)av.x * (float)bv.x + (float)av.y * (float)bv.y;
#endif
}

// ---- K0: full transpose f32 [d][j], f16 j-pair pack [jp][d], swj/bias ----
__global__ __launch_bounds__(256) void k_prep(const float* __restrict__ h,
                                              const float* __restrict__ w,
                                              const int* __restrict__ mk,
                                              float* __restrict__ hTf,
                                              unsigned int* __restrict__ hT16,
                                              float* __restrict__ swj,
                                              float* __restrict__ bias) {
  __shared__ __align__(16) float tile[32][132];
  __shared__ float wred[32][8];
  const int b  = blockIdx.x >> 5;
  const int jt = blockIdx.x & 31;
  const int tid = threadIdx.x;
  const float4* src = (const float4*)h + (size_t)(b * TT + jt * 32) * 32;
#pragma unroll
  for (int k = 0; k < 4; ++k) {
    int idx = k * 256 + tid;             // 0..1023
    float4 v = src[idx];
    int j = idx >> 5, c = idx & 31;
    *((float4*)&tile[j][c * 4]) = v;
  }
  __syncthreads();
  // hTf[d][j]
#pragma unroll
  for (int k = 0; k < 4; ++k) {
    int idx = k * 256 + tid;             // 0..1023
    int d = idx >> 3, jq = idx & 7;
    float4 v = {tile[jq * 4 + 0][d], tile[jq * 4 + 1][d],
                tile[jq * 4 + 2][d], tile[jq * 4 + 3][d]};
    *(float4*)&hTf[(size_t)(b * DD + d) * TT + jt * 32 + jq * 4] = v;
  }
  // hT16[jp][d]
#pragma unroll
  for (int k = 0; k < 2; ++k) {
    int idx = k * 256 + tid;             // 0..511
    int jp = idx >> 5, dq = idx & 31;
    uint4 wv;
    wv.x = pk16(tile[jp * 2][dq * 4 + 0], tile[jp * 2 + 1][dq * 4 + 0]);
    wv.y = pk16(tile[jp * 2][dq * 4 + 1], tile[jp * 2 + 1][dq * 4 + 1]);
    wv.z = pk16(tile[jp * 2][dq * 4 + 2], tile[jp * 2 + 1][dq * 4 + 2]);
    wv.w = pk16(tile[jp * 2][dq * 4 + 3], tile[jp * 2 + 1][dq * 4 + 3]);
    *(uint4*)&hT16[((size_t)(b * 512 + jt * 16 + jp)) * DD + dq * 4] = wv;
  }
  // wj
  {
    const int j = tid & 31, dg = tid >> 5;
    float p = 0.f;
#pragma unroll
    for (int e = 0; e < 16; e += 4) {
      float4 hv = *(const float4*)&tile[j][dg * 16 + e];
      float4 wv = *(const float4*)&w[dg * 16 + e];
      p += hv.x * wv.x + hv.y * wv.y + hv.z * wv.z + hv.w * wv.w;
    }
    wred[j][dg] = p;
  }
  __syncthreads();
  if (tid < 32) {
    const int row = b * TT + jt * 32 + tid;
    float a = 0.f;
#pragma unroll
    for (int e = 0; e < 8; ++e) a += wred[tid][e];
    const bool ok = (mk[row] != 0);
    swj[row]  = ok ? -a : 0.f;
    bias[row] = ok ? 0.f : kNegInf;
  }
}

// ---- K1: 8 rows x 256 j per block; 512 threads; wave = 1 row x 256 j ----
// grid = 256 rowgroups x 4 j-splits = 1024 blocks (4 blocks/CU, 32 waves/CU)
__global__ __launch_bounds__(512, 8) void k_fused(
    const float* __restrict__ h, const float* __restrict__ hTf,
    const unsigned int* __restrict__ hT16,
    const float* __restrict__ swj, const float* __restrict__ bias,
    float* __restrict__ ctxpart, float2* __restrict__ mlpart) {
  __shared__ __align__(16) unsigned int Pt[8][128];   // [row][jp], 4 KB

  const int tid  = threadIdx.x;
  const int lane = tid & 63;
  const int wv   = tid >> 6;                  // wave id = row in group
  const int rg   = blockIdx.x & 255;          // rowgroup (8 rows)
  const int js   = blockIdx.x >> 8;           // j-split 0..3
  const int b    = rg >> 7;
  const int urow = __builtin_amdgcn_readfirstlane((rg & 127) * 8 + wv);
  const float* hA  = h + ((size_t)b * TT + urow) * DD;   // wave-uniform base
  const int jv     = js * 256 + lane * 4;     // lane's j quad
  const float* hjb = hTf + (size_t)b * DD * TT;

  // ---------------- phase 1: distances, J=4 x R=1 ----------------
  float a0 = 0.f, a1 = 0.f, a2 = 0.f, a3 = 0.f;
#pragma unroll 2
  for (int c = 0; c < 16; ++c) {              // 8 dims per chunk
    float av[8];
    {
      const float4 t0 = *(const float4*)(hA + c * 8);
      const float4 t1 = *(const float4*)(hA + c * 8 + 4);
      av[0] = t0.x; av[1] = t0.y; av[2] = t0.z; av[3] = t0.w;
      av[4] = t1.x; av[5] = t1.y; av[6] = t1.z; av[7] = t1.w;
    }
#pragma unroll
    for (int e = 0; e < 8; ++e) {
      const float4 Bv = *(const float4*)(hjb + (size_t)(c * 8 + e) * TT + jv);
      a0 += fabsf(av[e] - Bv.x);
      a1 += fabsf(av[e] - Bv.y);
      a2 += fabsf(av[e] - Bv.z);
      a3 += fabsf(av[e] - Bv.w);
    }
  }

  // ---------------- softmax: pure wave-local ----------------
  const float4 swv = *(const float4*)(swj + (size_t)b * TT + jv);
  const float4 bvv = *(const float4*)(bias + (size_t)b * TT + jv);
  const float s0 = fmaf(swv.x, a0, bvv.x);
  const float s1 = fmaf(swv.y, a1, bvv.y);
  const float s2 = fmaf(swv.z, a2, bvv.z);
  const float s3 = fmaf(swv.w, a3, bvv.w);
  float m = fmaxf(fmaxf(s0, s1), fmaxf(s2, s3));
#pragma unroll
  for (int off = 32; off; off >>= 1) m = fmaxf(m, __shfl_xor(m, off));
  const float p0 = __expf(s0 - m), p1 = __expf(s1 - m);
  const float p2 = __expf(s2 - m), p3 = __expf(s3 - m);
  float l = (p0 + p1) + (p2 + p3);
#pragma unroll
  for (int off = 32; off; off >>= 1) l += __shfl_xor(l, off);
  {
    uint2 pw = {pk16(p0, p1), pk16(p2, p3)};
    *(uint2*)&Pt[wv][lane * 2] = pw;
  }
  if (lane == 0) mlpart[js * 2048 + rg * 8 + wv] = make_float2(m, l);
  __syncthreads();

  // ---------------- PV: wave sweeps its own row's 128 jp ----------------
  const unsigned int* Vp =
      hT16 + ((size_t)(b * 512 + js * 128)) * DD + lane * 2;
  float c0 = 0.f, c1 = 0.f;
#pragma unroll 2
  for (int q = 0; q < 32; ++q) {              // 4 jp per iter
    const uint4 Pw = *(const uint4*)&Pt[wv][q * 4];
    {
      const uint2 V = *(const uint2*)(Vp + (size_t)(q * 4 + 0) * DD);
      c0 = dot2f(Pw.x, V.x, c0); c1 = dot2f(Pw.x, V.y, c1);
    }
    {
      const uint2 V = *(const uint2*)(Vp + (size_t)(q * 4 + 1) * DD);
      c0 = dot2f(Pw.y, V.x, c0); c1 = dot2f(Pw.y, V.y, c1);
    }
    {
      const uint2 V = *(const uint2*)(Vp + (size_t)(q * 4 + 2) * DD);
      c0 = dot2f(Pw.z, V.x, c0); c1 = dot2f(Pw.z, V.y, c1);
    }
    {
      const uint2 V = *(const uint2*)(Vp + (size_t)(q * 4 + 3) * DD);
      c0 = dot2f(Pw.w, V.x, c0); c1 = dot2f(Pw.w, V.y, c1);
    }
  }
  *(float2*)&ctxpart[((size_t)(js * 2048 + rg * 8 + wv)) * DD + lane * 2] =
      make_float2(c0, c1);
}

// ---- K2: merge 4 j-split partials, normalize, write concat(h, ctx) ----
__global__ __launch_bounds__(256) void k_merge(const float* __restrict__ h,
                                               const float* __restrict__ ctxpart,
                                               const float2* __restrict__ mlpart,
                                               float* __restrict__ out) {
  const int row = blockIdx.x * 2 + (threadIdx.x >> 7);   // 0..2047
  const int d   = threadIdx.x & 127;

  float mg[4], lg[4];
#pragma unroll
  for (int g = 0; g < 4; ++g) {
    const float2 ml = mlpart[g * 2048 + row];
    mg[g] = ml.x; lg[g] = ml.y;
  }
  const float M = fmaxf(fmaxf(mg[0], mg[1]), fmaxf(mg[2], mg[3]));
  float L = 0.f, c = 0.f;
#pragma unroll
  for (int g = 0; g < 4; ++g) {
    const float wg = __expf(mg[g] - M);
    L = fmaf(lg[g], wg, L);
    c = fmaf(ctxpart[((size_t)(g * 2048 + row)) * DD + d], wg, c);
  }
  out[(size_t)row * 256 + d]       = h[(size_t)row * DD + d];
  out[(size_t)row * 256 + 128 + d] = c / L;
}

extern "C" void kernel_launch(void* const* d_in, const int* in_sizes, int n_in,
                              void* d_out, int out_size, void* d_ws, size_t ws_size,
                              hipStream_t stream) {
  const float* h  = (const float*)d_in[0];
  const int*   mk = (const int*)d_in[1];
  const float* w  = (const float*)d_in[2];
  float* out = (float*)d_out;

  char* ws = (char*)d_ws;
  float*        swj  = (float*)ws;                                   // 8 KB
  float*        bias = (float*)(ws + 8192);                          // 8 KB
  float*        hTf  = (float*)(ws + 16384);                         // 1 MB
  unsigned int* hT16 = (unsigned int*)(ws + 16384 + 1048576);        // 512 KB
  float*  ctxpart = (float*)(ws + 16384 + 1048576 + 524288);         // 4 MB
  float2* mlpart  = (float2*)(ws + 16384 + 1048576 + 524288 + 4194304);  // 64 KB

  hipLaunchKernelGGL(k_prep,  dim3(64),   dim3(256), 0, stream,
                     h, w, mk, hTf, hT16, swj, bias);
  hipLaunchKernelGGL(k_fused, dim3(1024), dim3(512), 0, stream,
                     h, hTf, hT16, swj, bias, ctxpart, mlpart);
  hipLaunchKernelGGL(k_merge, dim3(1024), dim3(256), 0, stream,
                     h, ctxpart, mlpart, out);
}

// Round 11
// 74.596 us; speedup vs baseline: 1.0390x; 1.0390x over previous
//
#include <hip/hip_runtime.h>
#include <math.h>

#define TT 1024
#define DD 128

static constexpr float kNegInf = -1e9f;

typedef __fp16 h2 __attribute__((ext_vector_type(2)));

__device__ __forceinline__ unsigned int pk16(float a, float b) {
  h2 v = __builtin_amdgcn_cvt_pkrtz(a, b);
  return __builtin_bit_cast(unsigned int, v);
}
__device__ __forceinline__ float dot2f(unsigned int a, unsigned int b, float c) {
#if __has_builtin(__builtin_amdgcn_fdot2)
  return __builtin_amdgcn_fdot2(__builtin_bit_cast(h2, a),
                                __builtin_bit_cast(h2, b), c, false);
#else
  h2 av = __builtin_bit_cast(h2, a), bv = __builtin_bit_cast(h2, b);
  return c + (float)av.x * (float)bv.x + (float)av.y * (float)bv.y;
#endif
}

// ---- K0: full transpose f32 [d][j], f16 j-pair pack [jp][d], swj/bias ----
__global__ __launch_bounds__(256) void k_prep(const float* __restrict__ h,
                                              const float* __restrict__ w,
                                              const int* __restrict__ mk,
                                              float* __restrict__ hTf,
                                              unsigned int* __restrict__ hT16,
                                              float* __restrict__ swj,
                                              float* __restrict__ bias) {
  __shared__ __align__(16) float tile[32][132];
  __shared__ float wred[32][8];
  const int b  = blockIdx.x >> 5;
  const int jt = blockIdx.x & 31;
  const int tid = threadIdx.x;
  const float4* src = (const float4*)h + (size_t)(b * TT + jt * 32) * 32;
#pragma unroll
  for (int k = 0; k < 4; ++k) {
    int idx = k * 256 + tid;             // 0..1023
    float4 v = src[idx];
    int j = idx >> 5, c = idx & 31;
    *((float4*)&tile[j][c * 4]) = v;
  }
  __syncthreads();
  // hTf[d][j]
#pragma unroll
  for (int k = 0; k < 4; ++k) {
    int idx = k * 256 + tid;             // 0..1023
    int d = idx >> 3, jq = idx & 7;
    float4 v = {tile[jq * 4 + 0][d], tile[jq * 4 + 1][d],
                tile[jq * 4 + 2][d], tile[jq * 4 + 3][d]};
    *(float4*)&hTf[(size_t)(b * DD + d) * TT + jt * 32 + jq * 4] = v;
  }
  // hT16[jp][d]
#pragma unroll
  for (int k = 0; k < 2; ++k) {
    int idx = k * 256 + tid;             // 0..511
    int jp = idx >> 5, dq = idx & 31;
    uint4 wv;
    wv.x = pk16(tile[jp * 2][dq * 4 + 0], tile[jp * 2 + 1][dq * 4 + 0]);
    wv.y = pk16(tile[jp * 2][dq * 4 + 1], tile[jp * 2 + 1][dq * 4 + 1]);
    wv.z = pk16(tile[jp * 2][dq * 4 + 2], tile[jp * 2 + 1][dq * 4 + 2]);
    wv.w = pk16(tile[jp * 2][dq * 4 + 3], tile[jp * 2 + 1][dq * 4 + 3]);
    *(uint4*)&hT16[((size_t)(b * 512 + jt * 16 + jp)) * DD + dq * 4] = wv;
  }
  // wj
  {
    const int j = tid & 31, dg = tid >> 5;
    float p = 0.f;
#pragma unroll
    for (int e = 0; e < 16; e += 4) {
      float4 hv = *(const float4*)&tile[j][dg * 16 + e];
      float4 wv = *(const float4*)&w[dg * 16 + e];
      p += hv.x * wv.x + hv.y * wv.y + hv.z * wv.z + hv.w * wv.w;
    }
    wred[j][dg] = p;
  }
  __syncthreads();
  if (tid < 32) {
    const int row = b * TT + jt * 32 + tid;
    float a = 0.f;
#pragma unroll
    for (int e = 0; e < 8; ++e) a += wred[tid][e];
    const bool ok = (mk[row] != 0);
    swj[row]  = ok ? -a : 0.f;
    bias[row] = ok ? 0.f : kNegInf;
  }
}

// ---- K1: 4 rows x 512 j per block; 256 thr; thread = J4 x R2 ----
// grid = 512 rowgroups x 2 j-halves = 1024 blocks (4 blocks/CU).
__global__ __launch_bounds__(256, 4) void k_fused(
    const float* __restrict__ h, const float* __restrict__ hTf,
    const unsigned int* __restrict__ hT16,
    const float* __restrict__ swj, const float* __restrict__ bias,
    float* __restrict__ ctxpart, float2* __restrict__ mlpart) {
  __shared__ __align__(16) unsigned int Pt[4][256];   // [row][jp_local], 4 KB
  __shared__ float wm[2][2][2];                       // [rpair][jsub][row01]
  __shared__ float wl[2][2][2];

  const int tid   = threadIdx.x;
  const int lane  = tid & 63;
  const int wv    = tid >> 6;
  const int rpair = wv >> 1;                 // row-pair within block
  const int jsub  = wv & 1;                  // j-quarter within block
  const int rg    = blockIdx.x & 511;        // rowgroup (4 rows)
  const int jh    = blockIdx.x >> 9;         // j-half 0..1
  const int b     = rg >> 8;
  const int lrow  = (rg & 255) * 4;          // first row within batch
  const int urow  = __builtin_amdgcn_readfirstlane(lrow + rpair * 2);
  const float* hA0 = h + ((size_t)b * TT + urow) * DD;   // wave-uniform
  const float* hA1 = hA0 + DD;
  const int jloc  = jh * 512 + jsub * 256 + lane * 4;    // j within batch
  const float* hjb = hTf + (size_t)b * DD * TT + jloc;

  // ---------------- phase 1: distances, J=4 x R=2 ----------------
  float acc0[4] = {0.f, 0.f, 0.f, 0.f};
  float acc1[4] = {0.f, 0.f, 0.f, 0.f};
#pragma unroll 2
  for (int c = 0; c < 16; ++c) {             // 8 dims per chunk
    const float4 A0a = *(const float4*)(hA0 + c * 8);
    const float4 A0b = *(const float4*)(hA0 + c * 8 + 4);
    const float4 A1a = *(const float4*)(hA1 + c * 8);
    const float4 A1b = *(const float4*)(hA1 + c * 8 + 4);
    const float a0[8] = {A0a.x, A0a.y, A0a.z, A0a.w, A0b.x, A0b.y, A0b.z, A0b.w};
    const float a1[8] = {A1a.x, A1a.y, A1a.z, A1a.w, A1b.x, A1b.y, A1b.z, A1b.w};
#pragma unroll
    for (int e = 0; e < 8; ++e) {
      const float4 Bv = *(const float4*)(hjb + (size_t)(c * 8 + e) * TT);
      acc0[0] += fabsf(a0[e] - Bv.x); acc0[1] += fabsf(a0[e] - Bv.y);
      acc0[2] += fabsf(a0[e] - Bv.z); acc0[3] += fabsf(a0[e] - Bv.w);
      acc1[0] += fabsf(a1[e] - Bv.x); acc1[1] += fabsf(a1[e] - Bv.y);
      acc1[2] += fabsf(a1[e] - Bv.z); acc1[3] += fabsf(a1[e] - Bv.w);
    }
  }

  // scores
  const float4 swv = *(const float4*)(swj + (size_t)b * TT + jloc);
  const float4 bvv = *(const float4*)(bias + (size_t)b * TT + jloc);
  float s0[4], s1[4];
  s0[0] = fmaf(swv.x, acc0[0], bvv.x); s0[1] = fmaf(swv.y, acc0[1], bvv.y);
  s0[2] = fmaf(swv.z, acc0[2], bvv.z); s0[3] = fmaf(swv.w, acc0[3], bvv.w);
  s1[0] = fmaf(swv.x, acc1[0], bvv.x); s1[1] = fmaf(swv.y, acc1[1], bvv.y);
  s1[2] = fmaf(swv.z, acc1[2], bvv.z); s1[3] = fmaf(swv.w, acc1[3], bvv.w);

  // per-wave max (256 j)
  float m0 = fmaxf(fmaxf(s0[0], s0[1]), fmaxf(s0[2], s0[3]));
  float m1 = fmaxf(fmaxf(s1[0], s1[1]), fmaxf(s1[2], s1[3]));
#pragma unroll
  for (int off = 32; off; off >>= 1) {
    m0 = fmaxf(m0, __shfl_xor(m0, off));
    m1 = fmaxf(m1, __shfl_xor(m1, off));
  }
  if (lane == 0) { wm[rpair][jsub][0] = m0; wm[rpair][jsub][1] = m1; }
  __syncthreads();
  const float M0 = fmaxf(wm[rpair][0][0], wm[rpair][1][0]);
  const float M1 = fmaxf(wm[rpair][0][1], wm[rpair][1][1]);

  // exp with block-row max, Pt write, per-wave sums
  const float p00 = __expf(s0[0] - M0), p01 = __expf(s0[1] - M0);
  const float p02 = __expf(s0[2] - M0), p03 = __expf(s0[3] - M0);
  const float p10 = __expf(s1[0] - M1), p11 = __expf(s1[1] - M1);
  const float p12 = __expf(s1[2] - M1), p13 = __expf(s1[3] - M1);
  float l0 = (p00 + p01) + (p02 + p03);
  float l1 = (p10 + p11) + (p12 + p13);
#pragma unroll
  for (int off = 32; off; off >>= 1) {
    l0 += __shfl_xor(l0, off);
    l1 += __shfl_xor(l1, off);
  }
  {
    uint2 w0 = {pk16(p00, p01), pk16(p02, p03)};
    uint2 w1 = {pk16(p10, p11), pk16(p12, p13)};
    *(uint2*)&Pt[rpair * 2 + 0][jsub * 128 + lane * 2] = w0;
    *(uint2*)&Pt[rpair * 2 + 1][jsub * 128 + lane * 2] = w1;
  }
  if (lane == 0) { wl[rpair][jsub][0] = l0; wl[rpair][jsub][1] = l1; }
  __syncthreads();

  // ---------------- PV: thread = (row=wv, dpair=lane), 256 jp ----------
  const int r  = wv;
  const int dp = lane;
  const unsigned int* Vp =
      hT16 + ((size_t)b * 512 + jh * 256) * DD + dp * 2;
  float c0 = 0.f, c1 = 0.f;
#pragma unroll 4
  for (int q = 0; q < 64; ++q) {             // 4 jp per iter
    const uint4 Pw = *(const uint4*)&Pt[r][q * 4];
    {
      const uint2 V = *(const uint2*)(Vp + (size_t)(q * 4 + 0) * DD);
      c0 = dot2f(Pw.x, V.x, c0); c1 = dot2f(Pw.x, V.y, c1);
    }
    {
      const uint2 V = *(const uint2*)(Vp + (size_t)(q * 4 + 1) * DD);
      c0 = dot2f(Pw.y, V.x, c0); c1 = dot2f(Pw.y, V.y, c1);
    }
    {
      const uint2 V = *(const uint2*)(Vp + (size_t)(q * 4 + 2) * DD);
      c0 = dot2f(Pw.z, V.x, c0); c1 = dot2f(Pw.z, V.y, c1);
    }
    {
      const uint2 V = *(const uint2*)(Vp + (size_t)(q * 4 + 3) * DD);
      c0 = dot2f(Pw.w, V.x, c0); c1 = dot2f(Pw.w, V.y, c1);
    }
  }
  const int slot = jh * 2048 + rg * 4 + r;
  *(float2*)&ctxpart[(size_t)slot * DD + dp * 2] = make_float2(c0, c1);
  if (lane == 0) {
    const float M = fmaxf(wm[r >> 1][0][r & 1], wm[r >> 1][1][r & 1]);
    const float L = wl[r >> 1][0][r & 1] + wl[r >> 1][1][r & 1];
    mlpart[slot] = make_float2(M, L);
  }
}

// ---- K2: merge 2 j-half partials, normalize, write concat(h, ctx) ----
__global__ __launch_bounds__(256) void k_merge(const float* __restrict__ h,
                                               const float* __restrict__ ctxpart,
                                               const float2* __restrict__ mlpart,
                                               float* __restrict__ out) {
  const int row = blockIdx.x * 2 + (threadIdx.x >> 7);   // 0..2047
  const int d   = threadIdx.x & 127;

  const float2 ml0 = mlpart[row];
  const float2 ml1 = mlpart[2048 + row];
  const float M  = fmaxf(ml0.x, ml1.x);
  const float w0 = __expf(ml0.x - M), w1 = __expf(ml1.x - M);
  const float L  = fmaf(ml0.y, w0, ml1.y * w1);
  const float c  = ctxpart[(size_t)row * DD + d] * w0 +
                   ctxpart[(size_t)(2048 + row) * DD + d] * w1;
  out[(size_t)row * 256 + d]       = h[(size_t)row * DD + d];
  out[(size_t)row * 256 + 128 + d] = c / L;
}

extern "C" void kernel_launch(void* const* d_in, const int* in_sizes, int n_in,
                              void* d_out, int out_size, void* d_ws, size_t ws_size,
                              hipStream_t stream) {
  const float* h  = (const float*)d_in[0];
  const int*   mk = (const int*)d_in[1];
  const float* w  = (const float*)d_in[2];
  float* out = (float*)d_out;

  char* ws = (char*)d_ws;
  float*        swj  = (float*)ws;                                   // 8 KB
  float*        bias = (float*)(ws + 8192);                          // 8 KB
  float*        hTf  = (float*)(ws + 16384);                         // 1 MB
  unsigned int* hT16 = (unsigned int*)(ws + 16384 + 1048576);        // 512 KB
  float*  ctxpart = (float*)(ws + 16384 + 1048576 + 524288);         // 2 MB
  float2* mlpart  = (float2*)(ws + 16384 + 1048576 + 524288 + 2097152);  // 32 KB

  hipLaunchKernelGGL(k_prep,  dim3(64),   dim3(256), 0, stream,
                     h, w, mk, hTf, hT16, swj, bias);
  hipLaunchKernelGGL(k_fused, dim3(1024), dim3(256), 0, stream,
                     h, hTf, hT16, swj, bias, ctxpart, mlpart);
  hipLaunchKernelGGL(k_merge, dim3(1024), dim3(256), 0, stream,
                     h, ctxpart, mlpart, out);
}

// Round 12
// 43.429 us; speedup vs baseline: 1.7846x; 1.7177x over previous
//
#include <hip/hip_runtime.h>
#include <math.h>

#define TT 1024
#define DD 128

static constexpr float kNegInf = -1e9f;

typedef __fp16 h2 __attribute__((ext_vector_type(2)));

__device__ __forceinline__ unsigned int pk16(float a, float b) {
  h2 v = __builtin_amdgcn_cvt_pkrtz(a, b);
  return __builtin_bit_cast(unsigned int, v);
}
__device__ __forceinline__ float dot2f(unsigned int a, unsigned int b, float c) {
#if __has_builtin(__builtin_amdgcn_fdot2)
  return __builtin_amdgcn_fdot2(__builtin_bit_cast(h2, a),
                                __builtin_bit_cast(h2, b), c, false);
#else
  h2 av = __builtin_bit_cast(h2, a), bv = __builtin_bit_cast(h2, b);
  return c + (float)av.x * (float)bv.x + (float)av.y * (float)bv.y;
#endif
}

// ---- K0: transpose f32 [d][j], f16 j-pair pack [jp][d], swj/bias ----
__global__ __launch_bounds__(256) void k_prep(const float* __restrict__ h,
                                              const float* __restrict__ w,
                                              const int* __restrict__ mk,
                                              float* __restrict__ hTf,
                                              unsigned int* __restrict__ hT16,
                                              float* __restrict__ swj,
                                              float* __restrict__ bias) {
  __shared__ __align__(16) float tile[32][132];
  __shared__ float wred[32][8];
  const int b  = blockIdx.x >> 5;
  const int jt = blockIdx.x & 31;
  const int tid = threadIdx.x;
  const float4* src = (const float4*)h + (size_t)(b * TT + jt * 32) * 32;
#pragma unroll
  for (int k = 0; k < 4; ++k) {
    int idx = k * 256 + tid;             // 0..1023
    float4 v = src[idx];
    int j = idx >> 5, c = idx & 31;
    *((float4*)&tile[j][c * 4]) = v;
  }
  __syncthreads();
  // hTf[d][j]
#pragma unroll
  for (int k = 0; k < 4; ++k) {
    int idx = k * 256 + tid;             // 0..1023
    int d = idx >> 3, jq = idx & 7;
    float4 v = {tile[jq * 4 + 0][d], tile[jq * 4 + 1][d],
                tile[jq * 4 + 2][d], tile[jq * 4 + 3][d]};
    *(float4*)&hTf[(size_t)(b * DD + d) * TT + jt * 32 + jq * 4] = v;
  }
  // hT16[jp][d]
#pragma unroll
  for (int k = 0; k < 2; ++k) {
    int idx = k * 256 + tid;             // 0..511
    int jp = idx >> 5, dq = idx & 31;
    uint4 wv;
    wv.x = pk16(tile[jp * 2][dq * 4 + 0], tile[jp * 2 + 1][dq * 4 + 0]);
    wv.y = pk16(tile[jp * 2][dq * 4 + 1], tile[jp * 2 + 1][dq * 4 + 1]);
    wv.z = pk16(tile[jp * 2][dq * 4 + 2], tile[jp * 2 + 1][dq * 4 + 2]);
    wv.w = pk16(tile[jp * 2][dq * 4 + 3], tile[jp * 2 + 1][dq * 4 + 3]);
    *(uint4*)&hT16[((size_t)(b * 512 + jt * 16 + jp)) * DD + dq * 4] = wv;
  }
  // wj
  {
    const int j = tid & 31, dg = tid >> 5;
    float p = 0.f;
#pragma unroll
    for (int e = 0; e < 16; e += 4) {
      float4 hv = *(const float4*)&tile[j][dg * 16 + e];
      float4 wv = *(const float4*)&w[dg * 16 + e];
      p += hv.x * wv.x + hv.y * wv.y + hv.z * wv.z + hv.w * wv.w;
    }
    wred[j][dg] = p;
  }
  __syncthreads();
  if (tid < 32) {
    const int row = b * TT + jt * 32 + tid;
    float a = 0.f;
#pragma unroll
    for (int e = 0; e < 8; ++e) a += wred[tid][e];
    const bool ok = (mk[row] != 0);
    swj[row]  = ok ? -a : 0.f;
    bias[row] = ok ? 0.f : kNegInf;
  }
}

// ---- K1: one block = 4 rows x FULL 1024 j; 256 thr; thread = J4 x R4 ----
// grid = 512 blocks. Complete softmax + PV + concat in-block (no merge).
__global__ __launch_bounds__(256, 2) void k_fused(
    const float* __restrict__ h, const float* __restrict__ hTf,
    const unsigned int* __restrict__ hT16,
    const float* __restrict__ swj, const float* __restrict__ bias,
    float* __restrict__ out) {
  __shared__ __align__(16) float A_lds[4][DD];     // 2 KB
  __shared__ __align__(16) unsigned int Pt[512][4];  // 8 KB [q][row]
  __shared__ __align__(16) float ctxp[4][4][DD];   // 8 KB [slice][row][d]
  __shared__ float redm[4][4];                     // [wave][row]
  __shared__ float redl[4][4];

  const int tid  = threadIdx.x;
  const int lane = tid & 63;
  const int wv   = tid >> 6;
  const int b    = blockIdx.x >> 8;
  const int row0 = (blockIdx.x & 255) * 4;         // row within batch

  // stage 4 A-rows into LDS (512 floats, float2 per thread)
  {
    const float2 v = *(const float2*)(h + ((size_t)b * TT + row0) * DD + tid * 2);
    *(float2*)&A_lds[0][tid * 2] = v;   // flat: A_lds[tid*2 /128][...]
  }
  __syncthreads();

  // ---------------- phase 1: distances, J=4 x R=4, explicit dbuf --------
  const int j = tid * 4;                           // this thread's j quad
  const float* Bb = hTf + (size_t)b * DD * TT + j;
  float acc[4][4];                                 // [u(j)][r(row)]
#pragma unroll
  for (int u = 0; u < 4; ++u)
#pragma unroll
    for (int r = 0; r < 4; ++r) acc[u][r] = 0.f;

#define LOADB4(B, s) {                                     \
    B[0] = *(const float4*)(Bb + (size_t)((s) * 4 + 0) * TT); \
    B[1] = *(const float4*)(Bb + (size_t)((s) * 4 + 1) * TT); \
    B[2] = *(const float4*)(Bb + (size_t)((s) * 4 + 2) * TT); \
    B[3] = *(const float4*)(Bb + (size_t)((s) * 4 + 3) * TT); }

#define COMP4(B, s) {                                                  \
    _Pragma("unroll") for (int r = 0; r < 4; ++r) {                    \
      const float4 Ar = *(const float4*)&A_lds[r][(s) * 4];            \
      _Pragma("unroll") for (int e = 0; e < 4; ++e) {                  \
        const float a = (e == 0) ? Ar.x : (e == 1) ? Ar.y              \
                        : (e == 2) ? Ar.z : Ar.w;                      \
        acc[0][r] += fabsf(a - B[e].x);                                \
        acc[1][r] += fabsf(a - B[e].y);                                \
        acc[2][r] += fabsf(a - B[e].z);                                \
        acc[3][r] += fabsf(a - B[e].w);                                \
      } } }

  {
    float4 B0[4], B1[4];
    LOADB4(B0, 0);
#pragma unroll 1
    for (int s = 0; s < 16; ++s) {
      LOADB4(B1, 2 * s + 1);             // unconditional: 2s+1 <= 31
      COMP4(B0, 2 * s);
      if (s < 15) LOADB4(B0, 2 * s + 2);
      COMP4(B1, 2 * s + 1);
    }
  }

  // scores
  const float4 swv = *(const float4*)(swj + (size_t)b * TT + j);
  const float4 bvv = *(const float4*)(bias + (size_t)b * TT + j);
  float sc[4][4];
#pragma unroll
  for (int r = 0; r < 4; ++r) {
    sc[0][r] = fmaf(swv.x, acc[0][r], bvv.x);
    sc[1][r] = fmaf(swv.y, acc[1][r], bvv.y);
    sc[2][r] = fmaf(swv.z, acc[2][r], bvv.z);
    sc[3][r] = fmaf(swv.w, acc[3][r], bvv.w);
  }

  // row max over full 1024 j
  {
    float mr[4];
#pragma unroll
    for (int r = 0; r < 4; ++r) {
      float m0 = fmaxf(fmaxf(sc[0][r], sc[1][r]), fmaxf(sc[2][r], sc[3][r]));
#pragma unroll
      for (int off = 32; off; off >>= 1) m0 = fmaxf(m0, __shfl_xor(m0, off));
      mr[r] = m0;
    }
    if (lane == 0) {
#pragma unroll
      for (int r = 0; r < 4; ++r) redm[wv][r] = mr[r];
    }
  }
  __syncthreads();
  float M[4];
#pragma unroll
  for (int r = 0; r < 4; ++r)
    M[r] = fmaxf(fmaxf(redm[0][r], redm[1][r]),
                 fmaxf(redm[2][r], redm[3][r]));

  // exp + pack P j-pairs + sums
  {
    float p[4][4];
    float ls[4] = {0.f, 0.f, 0.f, 0.f};
#pragma unroll
    for (int u = 0; u < 4; ++u)
#pragma unroll
      for (int r = 0; r < 4; ++r) {
        p[u][r] = __expf(sc[u][r] - M[r]);
        ls[r] += p[u][r];
      }
    uint4 w0 = {pk16(p[0][0], p[1][0]), pk16(p[0][1], p[1][1]),
                pk16(p[0][2], p[1][2]), pk16(p[0][3], p[1][3])};
    uint4 w1 = {pk16(p[2][0], p[3][0]), pk16(p[2][1], p[3][1]),
                pk16(p[2][2], p[3][2]), pk16(p[2][3], p[3][3])};
    *(uint4*)&Pt[tid * 2 + 0][0] = w0;
    *(uint4*)&Pt[tid * 2 + 1][0] = w1;
#pragma unroll
    for (int r = 0; r < 4; ++r) {
#pragma unroll
      for (int off = 32; off; off >>= 1) ls[r] += __shfl_xor(ls[r], off);
    }
    if (lane == 0) {
#pragma unroll
      for (int r = 0; r < 4; ++r) redl[wv][r] = ls[r];
    }
  }
  __syncthreads();

  // ---------------- PV: thread = (dpair 0..63) x (slice 0..3) ------------
  const int dp = tid & 63;
  const int s  = tid >> 6;
  const unsigned int* Vp =
      hT16 + ((size_t)(b * 512 + s * 128)) * DD + dp * 2;
  float cx[4][2];
#pragma unroll
  for (int r = 0; r < 4; ++r) { cx[r][0] = 0.f; cx[r][1] = 0.f; }
#pragma unroll 4
  for (int q = 0; q < 128; ++q) {
    const uint4 P = *(const uint4*)&Pt[s * 128 + q][0];   // broadcast
    const uint2 V = *(const uint2*)(Vp + (size_t)q * DD); // coalesced
    cx[0][0] = dot2f(P.x, V.x, cx[0][0]); cx[0][1] = dot2f(P.x, V.y, cx[0][1]);
    cx[1][0] = dot2f(P.y, V.x, cx[1][0]); cx[1][1] = dot2f(P.y, V.y, cx[1][1]);
    cx[2][0] = dot2f(P.z, V.x, cx[2][0]); cx[2][1] = dot2f(P.z, V.y, cx[2][1]);
    cx[3][0] = dot2f(P.w, V.x, cx[3][0]); cx[3][1] = dot2f(P.w, V.y, cx[3][1]);
  }
#pragma unroll
  for (int r = 0; r < 4; ++r)
    *(float2*)&ctxp[s][r][dp * 2] = make_float2(cx[r][0], cx[r][1]);
  __syncthreads();

  // ---------------- epilogue: reduce slices, normalize, concat ----------
#pragma unroll
  for (int k = 0; k < 2; ++k) {
    const int idx = tid + k * 256;        // 0..511
    const int r = idx >> 7, d = idx & 127;
    const float L = redl[0][r] + redl[1][r] + redl[2][r] + redl[3][r];
    const float c = (ctxp[0][r][d] + ctxp[1][r][d]) +
                    (ctxp[2][r][d] + ctxp[3][r][d]);
    const size_t row = (size_t)blockIdx.x * 4 + r;
    out[row * 256 + d]       = A_lds[r][d];
    out[row * 256 + 128 + d] = c / L;
  }
}

extern "C" void kernel_launch(void* const* d_in, const int* in_sizes, int n_in,
                              void* d_out, int out_size, void* d_ws, size_t ws_size,
                              hipStream_t stream) {
  const float* h  = (const float*)d_in[0];
  const int*   mk = (const int*)d_in[1];
  const float* w  = (const float*)d_in[2];
  float* out = (float*)d_out;

  char* ws = (char*)d_ws;
  float*        swj  = (float*)ws;                              // 8 KB
  float*        bias = (float*)(ws + 8192);                     // 8 KB
  float*        hTf  = (float*)(ws + 16384);                    // 1 MB
  unsigned int* hT16 = (unsigned int*)(ws + 16384 + 1048576);   // 512 KB

  hipLaunchKernelGGL(k_prep,  dim3(64),  dim3(256), 0, stream,
                     h, w, mk, hTf, hT16, swj, bias);
  hipLaunchKernelGGL(k_fused, dim3(512), dim3(256), 0, stream,
                     h, hTf, hT16, swj, bias, out);
}

// Round 13
// 43.328 us; speedup vs baseline: 1.7887x; 1.0023x over previous
//
#include <hip/hip_runtime.h>
#include <math.h>

#define TT 1024
#define DD 128

static constexpr float kNegInf = -1e9f;

typedef __fp16 h2 __attribute__((ext_vector_type(2)));

__device__ __forceinline__ unsigned int pk16(float a, float b) {
  h2 v = __builtin_amdgcn_cvt_pkrtz(a, b);
  return __builtin_bit_cast(unsigned int, v);
}
__device__ __forceinline__ float dot2f(unsigned int a, unsigned int b, float c) {
#if __has_builtin(__builtin_amdgcn_fdot2)
  return __builtin_amdgcn_fdot2(__builtin_bit_cast(h2, a),
                                __builtin_bit_cast(h2, b), c, false);
#else
  h2 av = __builtin_bit_cast(h2, a), bv = __builtin_bit_cast(h2, b);
  return c + (float)av.x * (float)bv.x + (float)av.y * (float)bv.y;
#endif
}

// ---- K0: transpose f32 [d][j], f16 j-pair pack [jp][d], swj/bias ----
__global__ __launch_bounds__(256) void k_prep(const float* __restrict__ h,
                                              const float* __restrict__ w,
                                              const int* __restrict__ mk,
                                              float* __restrict__ hTf,
                                              unsigned int* __restrict__ hT16,
                                              float* __restrict__ swj,
                                              float* __restrict__ bias) {
  __shared__ __align__(16) float tile[32][132];
  __shared__ float wred[32][8];
  const int b  = blockIdx.x >> 5;
  const int jt = blockIdx.x & 31;
  const int tid = threadIdx.x;
  const float4* src = (const float4*)h + (size_t)(b * TT + jt * 32) * 32;
#pragma unroll
  for (int k = 0; k < 4; ++k) {
    int idx = k * 256 + tid;             // 0..1023
    float4 v = src[idx];
    int j = idx >> 5, c = idx & 31;
    *((float4*)&tile[j][c * 4]) = v;
  }
  __syncthreads();
  // hTf[d][j]
#pragma unroll
  for (int k = 0; k < 4; ++k) {
    int idx = k * 256 + tid;             // 0..1023
    int d = idx >> 3, jq = idx & 7;
    float4 v = {tile[jq * 4 + 0][d], tile[jq * 4 + 1][d],
                tile[jq * 4 + 2][d], tile[jq * 4 + 3][d]};
    *(float4*)&hTf[(size_t)(b * DD + d) * TT + jt * 32 + jq * 4] = v;
  }
  // hT16[jp][d]
#pragma unroll
  for (int k = 0; k < 2; ++k) {
    int idx = k * 256 + tid;             // 0..511
    int jp = idx >> 5, dq = idx & 31;
    uint4 wv;
    wv.x = pk16(tile[jp * 2][dq * 4 + 0], tile[jp * 2 + 1][dq * 4 + 0]);
    wv.y = pk16(tile[jp * 2][dq * 4 + 1], tile[jp * 2 + 1][dq * 4 + 1]);
    wv.z = pk16(tile[jp * 2][dq * 4 + 2], tile[jp * 2 + 1][dq * 4 + 2]);
    wv.w = pk16(tile[jp * 2][dq * 4 + 3], tile[jp * 2 + 1][dq * 4 + 3]);
    *(uint4*)&hT16[((size_t)(b * 512 + jt * 16 + jp)) * DD + dq * 4] = wv;
  }
  // wj
  {
    const int j = tid & 31, dg = tid >> 5;
    float p = 0.f;
#pragma unroll
    for (int e = 0; e < 16; e += 4) {
      float4 hv = *(const float4*)&tile[j][dg * 16 + e];
      float4 wv = *(const float4*)&w[dg * 16 + e];
      p += hv.x * wv.x + hv.y * wv.y + hv.z * wv.z + hv.w * wv.w;
    }
    wred[j][dg] = p;
  }
  __syncthreads();
  if (tid < 32) {
    const int row = b * TT + jt * 32 + tid;
    float a = 0.f;
#pragma unroll
    for (int e = 0; e < 8; ++e) a += wred[tid][e];
    const bool ok = (mk[row] != 0);
    swj[row]  = ok ? -a : 0.f;
    bias[row] = ok ? 0.f : kNegInf;
  }
}

// ---- K1: one block = 4 rows x FULL 1024 j; 256 thr; thread = J4 x R4 ----
__global__ __launch_bounds__(256, 2) void k_fused(
    const float* __restrict__ h, const float* __restrict__ hTf,
    const unsigned int* __restrict__ hT16,
    const float* __restrict__ swj, const float* __restrict__ bias,
    float* __restrict__ out) {
  __shared__ __align__(16) float A_lds[4][DD];     // 2 KB
  __shared__ __align__(16) unsigned int Pt[512][4];  // 8 KB [q][row]
  __shared__ __align__(16) float ctxp[4][4][DD];   // 8 KB [slice][row][d]
  __shared__ float redm[4][4];                     // [wave][row]
  __shared__ float redl[4][4];

  const int tid  = threadIdx.x;
  const int lane = tid & 63;
  const int wv   = tid >> 6;
  const int b    = blockIdx.x >> 8;
  const int row0 = (blockIdx.x & 255) * 4;         // row within batch

  // stage 4 A-rows into LDS (512 floats, float2 per thread)
  {
    const float2 v = *(const float2*)(h + ((size_t)b * TT + row0) * DD + tid * 2);
    *(float2*)&A_lds[0][tid * 2] = v;
  }
  __syncthreads();

  // ---------------- phase 1: distances, J=4 x R=4, explicit dbuf --------
  const int j = tid * 4;                           // this thread's j quad
  const float* Bb = hTf + (size_t)b * DD * TT + j;
  float acc[4][4];                                 // [u(j)][r(row)]
#pragma unroll
  for (int u = 0; u < 4; ++u)
#pragma unroll
    for (int r = 0; r < 4; ++r) acc[u][r] = 0.f;

#define LOADB4(B, s) {                                     \
    B[0] = *(const float4*)(Bb + (size_t)((s) * 4 + 0) * TT); \
    B[1] = *(const float4*)(Bb + (size_t)((s) * 4 + 1) * TT); \
    B[2] = *(const float4*)(Bb + (size_t)((s) * 4 + 2) * TT); \
    B[3] = *(const float4*)(Bb + (size_t)((s) * 4 + 3) * TT); }

  // packed-pair distance: per (e,r): two float2 subs (v_pk_add_f32 w/ neg)
  // + 4 scalar abs-adds -> 6 instr per 4 pairs instead of 8.
#define COMP4(B, s) {                                                  \
    _Pragma("unroll") for (int r = 0; r < 4; ++r) {                    \
      const float4 Ar = *(const float4*)&A_lds[r][(s) * 4];            \
      _Pragma("unroll") for (int e = 0; e < 4; ++e) {                  \
        const float a = (e == 0) ? Ar.x : (e == 1) ? Ar.y              \
                        : (e == 2) ? Ar.z : Ar.w;                      \
        float2 dxy, dzw;                                               \
        dxy.x = a - B[e].x; dxy.y = a - B[e].y;                        \
        dzw.x = a - B[e].z; dzw.y = a - B[e].w;                        \
        acc[0][r] += fabsf(dxy.x);                                     \
        acc[1][r] += fabsf(dxy.y);                                     \
        acc[2][r] += fabsf(dzw.x);                                     \
        acc[3][r] += fabsf(dzw.y);                                     \
      } } }

  {
    float4 B0[4], B1[4];
    LOADB4(B0, 0);
#pragma unroll 1
    for (int s = 0; s < 16; ++s) {
      LOADB4(B1, 2 * s + 1);             // unconditional: 2s+1 <= 31
      COMP4(B0, 2 * s);
      if (s < 15) LOADB4(B0, 2 * s + 2);
      COMP4(B1, 2 * s + 1);
    }
  }

  // scores
  const float4 swv = *(const float4*)(swj + (size_t)b * TT + j);
  const float4 bvv = *(const float4*)(bias + (size_t)b * TT + j);
  float sc[4][4];
#pragma unroll
  for (int r = 0; r < 4; ++r) {
    sc[0][r] = fmaf(swv.x, acc[0][r], bvv.x);
    sc[1][r] = fmaf(swv.y, acc[1][r], bvv.y);
    sc[2][r] = fmaf(swv.z, acc[2][r], bvv.z);
    sc[3][r] = fmaf(swv.w, acc[3][r], bvv.w);
  }

  // row max over full 1024 j
  {
    float mr[4];
#pragma unroll
    for (int r = 0; r < 4; ++r) {
      float m0 = fmaxf(fmaxf(sc[0][r], sc[1][r]), fmaxf(sc[2][r], sc[3][r]));
#pragma unroll
      for (int off = 32; off; off >>= 1) m0 = fmaxf(m0, __shfl_xor(m0, off));
      mr[r] = m0;
    }
    if (lane == 0) {
#pragma unroll
      for (int r = 0; r < 4; ++r) redm[wv][r] = mr[r];
    }
  }
  __syncthreads();
  float M[4];
#pragma unroll
  for (int r = 0; r < 4; ++r)
    M[r] = fmaxf(fmaxf(redm[0][r], redm[1][r]),
                 fmaxf(redm[2][r], redm[3][r]));

  // exp + pack P j-pairs + sums
  {
    float p[4][4];
    float ls[4] = {0.f, 0.f, 0.f, 0.f};
#pragma unroll
    for (int u = 0; u < 4; ++u)
#pragma unroll
      for (int r = 0; r < 4; ++r) {
        p[u][r] = __expf(sc[u][r] - M[r]);
        ls[r] += p[u][r];
      }
    uint4 w0 = {pk16(p[0][0], p[1][0]), pk16(p[0][1], p[1][1]),
                pk16(p[0][2], p[1][2]), pk16(p[0][3], p[1][3])};
    uint4 w1 = {pk16(p[2][0], p[3][0]), pk16(p[2][1], p[3][1]),
                pk16(p[2][2], p[3][2]), pk16(p[2][3], p[3][3])};
    *(uint4*)&Pt[tid * 2 + 0][0] = w0;
    *(uint4*)&Pt[tid * 2 + 1][0] = w1;
#pragma unroll
    for (int r = 0; r < 4; ++r) {
#pragma unroll
      for (int off = 32; off; off >>= 1) ls[r] += __shfl_xor(ls[r], off);
    }
    if (lane == 0) {
#pragma unroll
      for (int r = 0; r < 4; ++r) redl[wv][r] = ls[r];
    }
  }
  __syncthreads();

  // ---------------- PV: thread = (dpair 0..63) x (slice 0..3) ------------
  const int dp = tid & 63;
  const int s  = tid >> 6;
  const unsigned int* Vp =
      hT16 + ((size_t)(b * 512 + s * 128)) * DD + dp * 2;
  float cx[4][2];
#pragma unroll
  for (int r = 0; r < 4; ++r) { cx[r][0] = 0.f; cx[r][1] = 0.f; }
#pragma unroll 4
  for (int q = 0; q < 128; ++q) {
    const uint4 P = *(const uint4*)&Pt[s * 128 + q][0];   // broadcast
    const uint2 V = *(const uint2*)(Vp + (size_t)q * DD); // coalesced
    cx[0][0] = dot2f(P.x, V.x, cx[0][0]); cx[0][1] = dot2f(P.x, V.y, cx[0][1]);
    cx[1][0] = dot2f(P.y, V.x, cx[1][0]); cx[1][1] = dot2f(P.y, V.y, cx[1][1]);
    cx[2][0] = dot2f(P.z, V.x, cx[2][0]); cx[2][1] = dot2f(P.z, V.y, cx[2][1]);
    cx[3][0] = dot2f(P.w, V.x, cx[3][0]); cx[3][1] = dot2f(P.w, V.y, cx[3][1]);
  }
#pragma unroll
  for (int r = 0; r < 4; ++r)
    *(float2*)&ctxp[s][r][dp * 2] = make_float2(cx[r][0], cx[r][1]);
  __syncthreads();

  // ---------------- epilogue: reduce slices, normalize, concat ----------
#pragma unroll
  for (int k = 0; k < 2; ++k) {
    const int idx = tid + k * 256;        // 0..511
    const int r = idx >> 7, d = idx & 127;
    const float L = redl[0][r] + redl[1][r] + redl[2][r] + redl[3][r];
    const float c = (ctxp[0][r][d] + ctxp[1][r][d]) +
                    (ctxp[2][r][d] + ctxp[3][r][d]);
    const size_t row = (size_t)blockIdx.x * 4 + r;
    out[row * 256 + d]       = A_lds[r][d];
    out[row * 256 + 128 + d] = c / L;
  }
}

extern "C" void kernel_launch(void* const* d_in, const int* in_sizes, int n_in,
                              void* d_out, int out_size, void* d_ws, size_t ws_size,
                              hipStream_t stream) {
  const float* h  = (const float*)d_in[0];
  const int*   mk = (const int*)d_in[1];
  const float* w  = (const float*)d_in[2];
  float* out = (float*)d_out;

  char* ws = (char*)d_ws;
  float*        swj  = (float*)ws;                              // 8 KB
  float*        bias = (float*)(ws + 8192);                     // 8 KB
  float*        hTf  = (float*)(ws + 16384);                    // 1 MB
  unsigned int* hT16 = (unsigned int*)(ws + 16384 + 1048576);   // 512 KB

  hipLaunchKernelGGL(k_prep,  dim3(64),  dim3(256), 0, stream,
                     h, w, mk, hTf, hT16, swj, bias);
  hipLaunchKernelGGL(k_fused, dim3(512), dim3(256), 0, stream,
                     h, hTf, hT16, swj, bias, out);
}